// Round 5
// baseline (292.782 us; speedup 1.0000x reference)
//
#include <hip/hip_runtime.h>
#include <math.h>
#include <stdint.h>

typedef __attribute__((ext_vector_type(8))) _Float16 half8;
typedef __attribute__((ext_vector_type(4))) _Float16 half4;
typedef __attribute__((ext_vector_type(4))) float f32x4;

constexpr int Bb = 8, Ll = 2500, Ee = 100, Nn = 8922;
constexpr int LP = 2560, EP = 128, NP = 8960;   // padded dims
constexpr int LT = 32;                          // l-tile (was 64)
constexpr int NTILES = LP / LT;                 // 80
constexpr int NTB = 128;                        // n per block (4 waves x 32)

constexpr size_t SZ_LF = (size_t)NP * EP * 2;
constexpr size_t SZ_XW = (size_t)Bb * LP * EP * 2;
constexpr size_t OFF_XW = SZ_LF;
constexpr size_t OFF_XT = OFF_XW + SZ_XW;
constexpr size_t WS_NEED = OFF_XT + SZ_XW;      // ~12.2 MB

__device__ __forceinline__ void gload16(const void* g, void* l) {
    __builtin_amdgcn_global_load_lds(
        (const __attribute__((address_space(1))) uint32_t*)g,
        (__attribute__((address_space(3))) uint32_t*)l, 16, 0, 0);
}

// ---------- prepass: lf -> f16 [NP][EP], bias col e=127 = 1.0 ----------
__global__ __launch_bounds__(256)
void prep_lf(const float* __restrict__ lf, uint32_t* __restrict__ dst) {
    int idx = blockIdx.x * 256 + threadIdx.x;   // n*64 + ep
    int n = idx >> 6, ep = idx & 63;
    int e0 = 2 * ep, e1 = e0 + 1;
    float f0 = (n < Nn && e0 < Ee) ? lf[(size_t)n * Ee + e0] : 0.f;
    float f1 = (n < Nn && e1 < Ee) ? lf[(size_t)n * Ee + e1] : (e1 == 127 ? 1.0f : 0.f);
    union { _Float16 h[2]; uint32_t u; } cv;
    cv.h[0] = (_Float16)f0; cv.h[1] = (_Float16)f1;
    dst[idx] = cv.u;
}

// ---------- fused prepass: x -> swizzled K rows [B][LP][EP] + swizzled V^T [B][EP][LP] ----------
// K swizzle: 16B blocks XOR'd by (l&7)<<4 within 256B rows (unchanged from R4).
// V swizzle: 16B blocks XOR'd by (e&3)<<4 within aligned 64B chunks (LT=32 rows).
__global__ __launch_bounds__(256)
void prep_x(const float* __restrict__ x, uint32_t* __restrict__ dxw,
            uint16_t* __restrict__ dxt) {
    __shared__ float lx[64][101];               // +1 pad
    const int l0 = blockIdx.x * 64;
    const int b  = blockIdx.y;
    for (int i = threadIdx.x; i < 64 * Ee; i += 256) {
        int ll = i / Ee, e = i - ll * Ee;
        int l = l0 + ll;
        lx[ll][e] = (l < Ll) ? x[((size_t)b * Ll + l) * Ee + e] : 0.f;
    }
    __syncthreads();
    // K rows
    for (int i = threadIdx.x; i < 64 * 64; i += 256) {
        int row = i >> 6, ep = i & 63;
        int l = l0 + row;
        int e0 = 2 * ep, e1 = e0 + 1;
        float f0 = (e0 < Ee) ? lx[row][e0] : 0.f;
        float f1;
        if (e1 < Ee)        f1 = lx[row][e1];
        else if (e1 == 127) f1 = (l < Ll) ? 0.f : -20000.f;   // softmax mask bias
        else                f1 = 0.f;
        union { _Float16 h[2]; uint32_t u; } cv;
        cv.h[0] = (_Float16)f0; cv.h[1] = (_Float16)f1;
        int boff = (4 * ep) ^ ((row & 7) << 4);
        dxw[((size_t)b * LP + l) * 64 + (boff >> 2)] = cv.u;
    }
    // V^T rows: [e][l], 16B-block swizzle keyed by (e&3) within 64B chunks
    for (int i = threadIdx.x; i < EP * 64; i += 256) {
        int e = i >> 6, ll = i & 63;
        float v = (e < Ee) ? lx[ll][e] : 0.f;
        uint32_t boff = (uint32_t)((2 * ll) ^ ((e & 3) << 4));  // stays in same 64B chunk
        union { _Float16 h; uint16_t u; } cv; cv.h = (_Float16)v;
        dxt[((size_t)b * EP + e) * LP + l0 + (boff >> 1)] = cv.u;
    }
}

// ---------- main: flash-style MFMA attention, LT=32, 40KB LDS, 4 blocks/CU ----------
__global__ __launch_bounds__(256, 4)
void cwa_mfma(const uint16_t* __restrict__ lf16, const uint16_t* __restrict__ xw,
              const uint16_t* __restrict__ xt, float* __restrict__ out) {
    __shared__ __align__(128) char smem[16384 + 16384 + 8192];   // Kx2, Vx2, P: 40 KB
    const int tid = threadIdx.x, lane = tid & 63, w = tid >> 6;  // w: 0..3
    const int g = lane >> 4, nl = lane & 15;
    const int b = blockIdx.y;
    const int n_base = blockIdx.x * NTB + w * 32;

    // Q fragments (B-operand): col n = nl (per 16-half), k = e = 32ks + 8g + j
    half8 qf[2][4];
#pragma unroll
    for (int nh = 0; nh < 2; nh++) {
        const uint16_t* qr = lf16 + (size_t)(n_base + 16 * nh + nl) * EP + 8 * g;
#pragma unroll
        for (int ks = 0; ks < 4; ks++) qf[nh][ks] = *(const half8*)(qr + 32 * ks);
    }

    f32x4 oacc[2][7];
#pragma unroll
    for (int nh = 0; nh < 2; nh++)
#pragma unroll
        for (int es = 0; es < 7; es++) oacc[nh][es] = f32x4{0.f, 0.f, 0.f, 0.f};
    float m_i[2] = {-INFINITY, -INFINITY}, s_i[2] = {0.f, 0.f};

    const char* xwb = (const char*)(xw + (size_t)b * LP * EP);
    const char* xtb = (const char*)(xt + (size_t)b * EP * LP);

    auto stage = [&](int t, int par) {
        char* kbuf = smem + par * 8192;
        char* vbuf = smem + 16384 + par * 8192;
        const char* kg = xwb + (size_t)t * LT * EP * 2;   // 8 KB tile
        const char* vg = xtb + (size_t)t * LT * 2;        // 64B per e-row
#pragma unroll
        for (int i = 0; i < 2; i++) {
            int off = i * 4096 + w * 1024 + lane * 16;
            gload16(kg + off, kbuf + off);
        }
#pragma unroll
        for (int i = 0; i < 2; i++) {
            int erow = i * 64 + w * 16 + (lane >> 2);
            gload16(vg + (size_t)erow * (LP * 2) + (lane & 3) * 16,
                    vbuf + i * 4096 + w * 1024 + lane * 16);
        }
    };

    stage(0, 0);
    asm volatile("s_waitcnt vmcnt(0)" ::: "memory");
    __syncthreads();

    char* pb = smem + 32768 + w * 2048;     // wave-private P: 32 rows x 64B
    const int swp = (nl & 3) << 4;

    for (int t = 0; t < NTILES; t++) {
        const int par = t & 1;
        const char* kb = smem + par * 8192;
        const char* vb = smem + 16384 + par * 8192;

        if (t + 1 < NTILES) stage(t + 1, par ^ 1);

        // ---- QK^T: S^T[l][n] = mfma(A=K, B=Q), each kf feeds both n-halves ----
        f32x4 sacc[2][2];
#pragma unroll
        for (int nh = 0; nh < 2; nh++)
#pragma unroll
            for (int ls = 0; ls < 2; ls++) sacc[nh][ls] = f32x4{0.f, 0.f, 0.f, 0.f};
#pragma unroll
        for (int ls = 0; ls < 2; ls++) {
            const int lrow = 16 * ls + nl;
            const char* kr = kb + lrow * 256;
            const int sw = (lrow & 7) << 4;
#pragma unroll
            for (int ks = 0; ks < 4; ks++) {
                half8 kf = *(const half8*)(kr + ((64 * ks + 16 * g) ^ sw));
                sacc[0][ls] = __builtin_amdgcn_mfma_f32_16x16x32_f16(kf, qf[0][ks], sacc[0][ls], 0, 0, 0);
                sacc[1][ls] = __builtin_amdgcn_mfma_f32_16x16x32_f16(kf, qf[1][ks], sacc[1][ls], 0, 0, 0);
            }
        }

        // ---- tile max per n (tree + 2 shfl) ----
        float tm[2];
#pragma unroll
        for (int nh = 0; nh < 2; nh++) {
            float a0 = fmaxf(fmaxf(sacc[nh][0][0], sacc[nh][0][1]),
                             fmaxf(sacc[nh][0][2], sacc[nh][0][3]));
            float a1 = fmaxf(fmaxf(sacc[nh][1][0], sacc[nh][1][1]),
                             fmaxf(sacc[nh][1][2], sacc[nh][1][3]));
            float tmv = fmaxf(a0, a1);
            tmv = fmaxf(tmv, __shfl_xor(tmv, 16, 64));
            tmv = fmaxf(tmv, __shfl_xor(tmv, 32, 64));
            tm[nh] = tmv;
        }

        // ---- defer-max (T13): rescale only when max grew past m_i + 8 ----
        if (!__all((tm[0] <= m_i[0] + 8.f) && (tm[1] <= m_i[1] + 8.f))) {
#pragma unroll
            for (int nh = 0; nh < 2; nh++) {
                const float mn = fmaxf(m_i[nh], tm[nh]);
                const float sc = __expf(m_i[nh] - mn);   // first tile: exp(-inf)=0
                m_i[nh] = mn;
                s_i[nh] *= sc;
#pragma unroll
                for (int r = 0; r < 4; r++) {
                    float scr = __shfl(sc, 4 * g + r, 64);
#pragma unroll
                    for (int es = 0; es < 7; es++) oacc[nh][es][r] *= scr;
                }
            }
        }

        // ---- P = exp(S - m), sum, write to wave-private LDS ----
#pragma unroll
        for (int nh = 0; nh < 2; nh++) {
            float ts = 0.f;
            half4 ph[2];
#pragma unroll
            for (int ls = 0; ls < 2; ls++)
#pragma unroll
                for (int r = 0; r < 4; r++) {
                    float pv = __expf(sacc[nh][ls][r] - m_i[nh]);   // bounded by e^8
                    ts += pv;
                    ph[ls][r] = (_Float16)pv;
                }
            ts += __shfl_xor(ts, 16, 64);
            ts += __shfl_xor(ts, 32, 64);
            s_i[nh] += ts;
#pragma unroll
            for (int ls = 0; ls < 2; ls++)
                *(half4*)(pb + (16 * nh + nl) * 64 + ((32 * ls + 8 * g) ^ swp)) = ph[ls];
        }

        // ---- PV: D[n][e] += mfma(A=P, B=V), each vf feeds both n-halves ----
        {
            half8 pf0 = *(const half8*)(pb + nl * 64 + ((16 * g) ^ swp));
            half8 pf1 = *(const half8*)(pb + (16 + nl) * 64 + ((16 * g) ^ swp));
#pragma unroll
            for (int es = 0; es < 7; es++) {
                const int er = 16 * es + nl;
                half8 vf = *(const half8*)(vb + er * 64 + ((16 * g) ^ ((er & 3) << 4)));
                oacc[0][es] = __builtin_amdgcn_mfma_f32_16x16x32_f16(pf0, vf, oacc[0][es], 0, 0, 0);
                oacc[1][es] = __builtin_amdgcn_mfma_f32_16x16x32_f16(pf1, vf, oacc[1][es], 0, 0, 0);
            }
        }

        asm volatile("s_waitcnt vmcnt(0)" ::: "memory");   // stale: issued a full tile ago
        __syncthreads();
    }

    // ---- epilogue ----
#pragma unroll
    for (int nh = 0; nh < 2; nh++) {
        const float inv = 1.0f / s_i[nh];
#pragma unroll
        for (int r = 0; r < 4; r++) {
            const float invr = __shfl(inv, 4 * g + r, 64);
            const int n = n_base + 16 * nh + 4 * g + r;
            if (n < Nn) {
#pragma unroll
                for (int es = 0; es < 7; es++) {
                    const int e = 16 * es + nl;
                    if (e < Ee) out[((size_t)b * Nn + n) * Ee + e] = oacc[nh][es][r] * invr;
                }
            }
        }
    }
}

// ---------- fp32 fallback (verified R1 kernel) for ws too small ----------
constexpr int FNT = 16, FLT = 64, FLTP = 65;
__global__ __launch_bounds__(256)
void cwa_fwd(const float* __restrict__ x, const float* __restrict__ lf,
             float* __restrict__ out) {
    __shared__ float q[FNT][Ee];
    __shared__ float xts[Ee][FLTP];
    __shared__ float pl[FNT][FLT];
    const int tid = threadIdx.x, lane = tid & 63, w = tid >> 6;
    const int b = blockIdx.y, n0 = blockIdx.x * FNT;
    for (int idx = tid; idx < FNT * Ee; idx += 256) {
        int nl = idx / Ee, e = idx - nl * Ee;
        int n = n0 + nl;
        q[nl][e] = (n < Nn) ? lf[n * Ee + e] : 0.0f;
    }
    float m_i[4], s_i[4], a0[4], a1[4];
#pragma unroll
    for (int i = 0; i < 4; i++) { m_i[i] = -INFINITY; s_i[i] = 0.f; a0[i] = 0.f; a1[i] = 0.f; }
    const float* xb = x + (size_t)b * Ll * Ee;
    const bool hi_ok = lane < (Ee - 64);
    for (int l0 = 0; l0 < Ll; l0 += FLT) {
        const int nrows = min(FLT, Ll - l0);
        __syncthreads();
        for (int idx = tid; idx < FLT * (Ee / 4); idx += 256) {
            int r = idx / (Ee / 4), c4 = idx - r * (Ee / 4);
            float4 v = make_float4(0.f, 0.f, 0.f, 0.f);
            if (r < nrows) v = *reinterpret_cast<const float4*>(xb + (size_t)(l0 + r) * Ee + c4 * 4);
            xts[c4 * 4 + 0][r] = v.x; xts[c4 * 4 + 1][r] = v.y;
            xts[c4 * 4 + 2][r] = v.z; xts[c4 * 4 + 3][r] = v.w;
        }
        __syncthreads();
        float sc[4] = {0.f, 0.f, 0.f, 0.f};
        for (int e = 0; e < Ee; e++) {
            float xv = xts[e][lane];
#pragma unroll
            for (int i = 0; i < 4; i++) sc[i] = fmaf(q[4 * w + i][e], xv, sc[i]);
        }
        const bool valid = lane < nrows;
#pragma unroll
        for (int i = 0; i < 4; i++) {
            float s = valid ? sc[i] : -INFINITY;
            float tmv = s;
#pragma unroll
            for (int msk = 32; msk >= 1; msk >>= 1) tmv = fmaxf(tmv, __shfl_xor(tmv, msk, 64));
            float mn = fmaxf(m_i[i], tmv);
            float p = __expf(s - mn);
            float sm = p;
#pragma unroll
            for (int msk = 32; msk >= 1; msk >>= 1) sm += __shfl_xor(sm, msk, 64);
            float scl = __expf(m_i[i] - mn);
            s_i[i] = s_i[i] * scl + sm; m_i[i] = mn;
            a0[i] *= scl; a1[i] *= scl;
            pl[4 * w + i][lane] = p;
        }
        __syncthreads();
#pragma unroll 4
        for (int l = 0; l < FLT; l++) {
            float xv0 = xts[lane][l];
            float xv1 = hi_ok ? xts[64 + lane][l] : 0.f;
#pragma unroll
            for (int i = 0; i < 4; i++) {
                float pv = pl[4 * w + i][l];
                a0[i] = fmaf(pv, xv0, a0[i]); a1[i] = fmaf(pv, xv1, a1[i]);
            }
        }
    }
#pragma unroll
    for (int i = 0; i < 4; i++) {
        int n = n0 + 4 * w + i;
        if (n >= Nn) continue;
        float inv = 1.0f / s_i[i];
        size_t base = ((size_t)b * Nn + n) * Ee;
        out[base + lane] = a0[i] * inv;
        if (hi_ok) out[base + 64 + lane] = a1[i] * inv;
    }
}

extern "C" void kernel_launch(void* const* d_in, const int* in_sizes, int n_in,
                              void* d_out, int out_size, void* d_ws, size_t ws_size,
                              hipStream_t stream) {
    const float* x  = (const float*)d_in[0];   // [8, 2500, 100]
    const float* lf = (const float*)d_in[1];   // [8922, 100]
    float* out = (float*)d_out;                // [8, 8922, 100]
    if (ws_size >= WS_NEED) {
        prep_lf<<<NP * 64 / 256, 256, 0, stream>>>(lf, (uint32_t*)d_ws);
        prep_x<<<dim3(LP / 64, Bb), 256, 0, stream>>>(
            x, (uint32_t*)((char*)d_ws + OFF_XW), (uint16_t*)((char*)d_ws + OFF_XT));
        cwa_mfma<<<dim3(NP / NTB, Bb), 256, 0, stream>>>(
            (const uint16_t*)d_ws, (const uint16_t*)((char*)d_ws + OFF_XW),
            (const uint16_t*)((char*)d_ws + OFF_XT), out);
    } else {
        dim3 grid((Nn + FNT - 1) / FNT, Bb);
        cwa_fwd<<<grid, dim3(256), 0, stream>>>(x, lf, out);
    }
}

// Round 6
// 238.609 us; speedup vs baseline: 1.2270x; 1.2270x over previous
//
#include <hip/hip_runtime.h>
#include <math.h>
#include <stdint.h>

typedef __attribute__((ext_vector_type(8))) _Float16 half8;
typedef __attribute__((ext_vector_type(4))) _Float16 half4;
typedef __attribute__((ext_vector_type(4))) float f32x4;

constexpr int Bb = 8, Ll = 2500, Ee = 100, Nn = 8922;
constexpr int LP = 2560, EP = 128;
constexpr int NP = 9024;                         // 47 * 192
constexpr int VE = 112;                          // staged V^T rows (>= 16*7)
constexpr int LT = 64;
constexpr int NTILES = LP / LT;                  // 40
constexpr int NTB = 192;                         // 4 waves x 48 n (3 frags)
constexpr int NH = 3;

constexpr size_t SZ_LF = (size_t)NP * EP * 2;            // 2.31 MB
constexpr size_t SZ_XW = (size_t)Bb * LP * EP * 2;       // 5.24 MB
constexpr size_t SZ_XT = (size_t)Bb * VE * LP * 2;       // 4.59 MB
constexpr size_t OFF_XW = SZ_LF;
constexpr size_t OFF_XT = OFF_XW + SZ_XW;
constexpr size_t WS_NEED = OFF_XT + SZ_XT;               // ~12.14 MB

__device__ __forceinline__ void gload16(const void* g, void* l) {
    __builtin_amdgcn_global_load_lds(
        (const __attribute__((address_space(1))) uint32_t*)g,
        (__attribute__((address_space(3))) uint32_t*)l, 16, 0, 0);
}

// ---------- fused prepass ----------
// y<8 : x[b] -> swizzled K rows [B][LP][EP] f16 (bias e=127) + swizzled V^T [B][VE][LP] f16
// y==8: lf -> f16 [NP][EP], bias col e=127 = 1.0
__global__ __launch_bounds__(256)
void prep_all(const float* __restrict__ x, const float* __restrict__ lf,
              uint32_t* __restrict__ dlf, uint32_t* __restrict__ dxw,
              uint16_t* __restrict__ dxt) {
    if (blockIdx.y == Bb) {
        for (int idx = blockIdx.x * 256 + threadIdx.x; idx < NP * 64; idx += 40 * 256) {
            int n = idx >> 6, ep = idx & 63;
            int e0 = 2 * ep, e1 = e0 + 1;
            float f0 = (n < Nn && e0 < Ee) ? lf[(size_t)n * Ee + e0] : 0.f;
            float f1 = (n < Nn && e1 < Ee) ? lf[(size_t)n * Ee + e1] : (e1 == 127 ? 1.0f : 0.f);
            union { _Float16 h[2]; uint32_t u; } cv;
            cv.h[0] = (_Float16)f0; cv.h[1] = (_Float16)f1;
            dlf[idx] = cv.u;
        }
        return;
    }
    __shared__ float lx[64][101];               // +1 pad
    const int l0 = blockIdx.x * 64;
    const int b  = blockIdx.y;
    for (int i = threadIdx.x; i < 64 * Ee; i += 256) {
        int ll = i / Ee, e = i - ll * Ee;
        int l = l0 + ll;
        lx[ll][e] = (l < Ll) ? x[((size_t)b * Ll + l) * Ee + e] : 0.f;
    }
    __syncthreads();
    // K rows: 16B-block swizzle keyed by (l&7) within 128B half-row; mask bias e=127
    for (int i = threadIdx.x; i < 64 * 64; i += 256) {
        int row = i >> 6, ep = i & 63;
        int l = l0 + row;
        int e0 = 2 * ep, e1 = e0 + 1;
        float f0 = (e0 < Ee) ? lx[row][e0] : 0.f;
        float f1;
        if (e1 < Ee)        f1 = lx[row][e1];
        else if (e1 == 127) f1 = (l < Ll) ? 0.f : -20000.f;   // softmax mask bias
        else                f1 = 0.f;
        union { _Float16 h[2]; uint32_t u; } cv;
        cv.h[0] = (_Float16)f0; cv.h[1] = (_Float16)f1;
        int boff = (4 * ep) ^ ((row & 7) << 4);
        dxw[((size_t)b * LP + l) * 64 + (boff >> 2)] = cv.u;
    }
    // V^T rows: [e][l], 16B-block swizzle keyed by (e&7) within each tile's 128B
    for (int i = threadIdx.x; i < VE * 64; i += 256) {
        int e = i >> 6, ll = i & 63;
        float v = (e < Ee) ? lx[ll][e] : 0.f;
        uint32_t boff = (uint32_t)((2 * ll) ^ ((e & 7) << 4));
        union { _Float16 h; uint16_t u; } cv; cv.h = (_Float16)v;
        dxt[((size_t)b * VE + e) * LP + l0 + (boff >> 1)] = cv.u;
    }
}

// ---------- main: flash-style MFMA attention, 48 n per wave, single-V pipeline ----------
__global__ __launch_bounds__(256, 2)
void cwa_mfma(const uint16_t* __restrict__ lf16, const uint16_t* __restrict__ xw,
              const uint16_t* __restrict__ xt, float* __restrict__ out) {
    // K dbuf 2x16K @0 | V 14K @32768 | P 4x6K @47104  => 70 KB
    __shared__ __align__(128) char smem[71680];
    const int tid = threadIdx.x, lane = tid & 63, w = tid >> 6;  // w: 0..3
    const int g = lane >> 4, nl = lane & 15;
    const int b = blockIdx.y;
    const int n_base = blockIdx.x * NTB + w * 48;

    const char* xwb = (const char*)(xw + (size_t)b * LP * EP);
    const char* xtb = (const char*)(xt + (size_t)b * VE * LP);

    auto stage_k = [&](int t, int p) {
        const char* kg = xwb + (size_t)t * (LT * EP * 2);
        char* kbuf = smem + p * 16384;
#pragma unroll
        for (int i = 0; i < 4; i++) {
            int off = i * 4096 + tid * 16;
            gload16(kg + off, kbuf + off);
        }
    };
    auto stage_v = [&](int t) {
        const char* vg = xtb + (size_t)t * (LT * 2);
        char* vbuf = smem + 32768;
#pragma unroll
        for (int i = 0; i < 3; i++) {
            int u = i * 256 + tid;
            gload16(vg + (size_t)(u >> 3) * (LP * 2) + (u & 7) * 16, vbuf + u * 16);
        }
        if (tid < 128) {
            int u = 768 + tid;
            gload16(vg + (size_t)(u >> 3) * (LP * 2) + (u & 7) * 16, vbuf + u * 16);
        }
    };

    // stage tile 0 (K+V)
    stage_k(0, 0);
    stage_v(0);

    // Q fragments: col n = nl (per 16-block), k = e = 32ks + 8g + j
    half8 qf[NH][4];
#pragma unroll
    for (int nh = 0; nh < NH; nh++) {
        const uint16_t* qr = lf16 + (size_t)(n_base + 16 * nh + nl) * EP + 8 * g;
#pragma unroll
        for (int ks = 0; ks < 4; ks++) qf[nh][ks] = *(const half8*)(qr + 32 * ks);
    }
    asm volatile("s_waitcnt vmcnt(0)" ::: "memory");   // qf + tile0 all landed
    __syncthreads();
    stage_k(1, 1);                                     // 4 loads in flight

    f32x4 oacc[NH][7];
#pragma unroll
    for (int nh = 0; nh < NH; nh++)
#pragma unroll
        for (int es = 0; es < 7; es++) oacc[nh][es] = f32x4{0.f, 0.f, 0.f, 0.f};
    float m_i[NH] = {-INFINITY, -INFINITY, -INFINITY}, s_i[NH] = {0.f, 0.f, 0.f};

    const char* vb = smem + 32768;
    char* pb = smem + 47104 + w * 6144;     // wave-private P: 48 rows x 128B
    const int swp = (nl & 7) << 4;

    for (int t = 0; t < NTILES; t++) {
        const int p = t & 1;
        const char* kb = smem + p * 16384;

        // ---- QK^T: S^T[l][n] = mfma(A=K, B=Q); each kf feeds 3 n-blocks ----
        f32x4 sacc[NH][4];
#pragma unroll
        for (int nh = 0; nh < NH; nh++)
#pragma unroll
            for (int ls = 0; ls < 4; ls++) sacc[nh][ls] = f32x4{0.f, 0.f, 0.f, 0.f};
#pragma unroll
        for (int ls = 0; ls < 4; ls++) {
            const int lrow = 16 * ls + nl;
            const char* kr = kb + lrow * 256;
            const int sw = (lrow & 7) << 4;
#pragma unroll
            for (int ks = 0; ks < 4; ks++) {
                half8 kf = *(const half8*)(kr + ((64 * ks + 16 * g) ^ sw));
                sacc[0][ls] = __builtin_amdgcn_mfma_f32_16x16x32_f16(kf, qf[0][ks], sacc[0][ls], 0, 0, 0);
                sacc[1][ls] = __builtin_amdgcn_mfma_f32_16x16x32_f16(kf, qf[1][ks], sacc[1][ls], 0, 0, 0);
                sacc[2][ls] = __builtin_amdgcn_mfma_f32_16x16x32_f16(kf, qf[2][ks], sacc[2][ls], 0, 0, 0);
            }
        }

        // ---- tile max per n ----
        float tm[NH];
#pragma unroll
        for (int nh = 0; nh < NH; nh++) {
            float a0 = fmaxf(fmaxf(sacc[nh][0][0], sacc[nh][0][1]), fmaxf(sacc[nh][0][2], sacc[nh][0][3]));
            float a1 = fmaxf(fmaxf(sacc[nh][1][0], sacc[nh][1][1]), fmaxf(sacc[nh][1][2], sacc[nh][1][3]));
            float a2 = fmaxf(fmaxf(sacc[nh][2][0], sacc[nh][2][1]), fmaxf(sacc[nh][2][2], sacc[nh][2][3]));
            float a3 = fmaxf(fmaxf(sacc[nh][3][0], sacc[nh][3][1]), fmaxf(sacc[nh][3][2], sacc[nh][3][3]));
            float tmv = fmaxf(fmaxf(a0, a1), fmaxf(a2, a3));
            tmv = fmaxf(tmv, __shfl_xor(tmv, 16, 64));
            tmv = fmaxf(tmv, __shfl_xor(tmv, 32, 64));
            tm[nh] = tmv;
        }

        // ---- defer-max (T13): rescale only when max grew past m_i + 8 ----
        if (!__all((tm[0] <= m_i[0] + 8.f) && (tm[1] <= m_i[1] + 8.f) && (tm[2] <= m_i[2] + 8.f))) {
#pragma unroll
            for (int nh = 0; nh < NH; nh++) {
                const float mn = fmaxf(m_i[nh], tm[nh]);
                const float sc = __expf(m_i[nh] - mn);   // first tile: exp(-inf)=0
                m_i[nh] = mn;
                s_i[nh] *= sc;
#pragma unroll
                for (int r = 0; r < 4; r++) {
                    float scr = __shfl(sc, 4 * g + r, 64);
#pragma unroll
                    for (int es = 0; es < 7; es++) oacc[nh][es][r] *= scr;
                }
            }
        }

        // ---- P = exp(S - m) (bounded by e^8), sum, write to wave-private LDS ----
#pragma unroll
        for (int nh = 0; nh < NH; nh++) {
            float ts = 0.f;
            half4 ph[4];
#pragma unroll
            for (int ls = 0; ls < 4; ls++)
#pragma unroll
                for (int r = 0; r < 4; r++) {
                    float pv = __expf(sacc[nh][ls][r] - m_i[nh]);
                    ts += pv;
                    ph[ls][r] = (_Float16)pv;
                }
            ts += __shfl_xor(ts, 16, 64);
            ts += __shfl_xor(ts, 32, 64);
            s_i[nh] += ts;
#pragma unroll
            for (int ls = 0; ls < 4; ls++)
                *(half4*)(pb + (16 * nh + nl) * 128 + ((32 * ls + 8 * g) ^ swp)) = ph[ls];
        }

        // ---- PV: D[n][e] += mfma(A=P, B=V); each vf feeds 3 n-blocks ----
#pragma unroll
        for (int kl = 0; kl < 2; kl++) {
            half8 pf0 = *(const half8*)(pb + nl * 128 + ((64 * kl + 16 * g) ^ swp));
            half8 pf1 = *(const half8*)(pb + (16 + nl) * 128 + ((64 * kl + 16 * g) ^ swp));
            half8 pf2 = *(const half8*)(pb + (32 + nl) * 128 + ((64 * kl + 16 * g) ^ swp));
#pragma unroll
            for (int es = 0; es < 7; es++) {
                const int er = 16 * es + nl;
                half8 vf = *(const half8*)(vb + er * 128 + ((64 * kl + 16 * g) ^ ((er & 7) << 4)));
                oacc[0][es] = __builtin_amdgcn_mfma_f32_16x16x32_f16(pf0, vf, oacc[0][es], 0, 0, 0);
                oacc[1][es] = __builtin_amdgcn_mfma_f32_16x16x32_f16(pf1, vf, oacc[1][es], 0, 0, 0);
                oacc[2][es] = __builtin_amdgcn_mfma_f32_16x16x32_f16(pf2, vf, oacc[2][es], 0, 0, 0);
            }
        }

        __syncthreads();                           // all waves done with vb & kb[p]
        const int tv = min(t + 1, NTILES - 1);
        const int tk = min(t + 2, NTILES - 1);
        stage_v(tv);                               // into vb
        stage_k(tk, p);                            // into kb[p] (now free)
        // wait K(t+1)+V(t+1) landed; K(t+2)'s 4 loads stay in flight across the barrier
        asm volatile("s_waitcnt vmcnt(4)" ::: "memory");
        __syncthreads();
    }

    // ---- epilogue ----
#pragma unroll
    for (int nh = 0; nh < NH; nh++) {
        const float inv = 1.0f / s_i[nh];
#pragma unroll
        for (int r = 0; r < 4; r++) {
            const float invr = __shfl(inv, 4 * g + r, 64);
            const int n = n_base + 16 * nh + 4 * g + r;
            if (n < Nn) {
#pragma unroll
                for (int es = 0; es < 7; es++) {
                    const int e = 16 * es + nl;
                    if (e < Ee) out[((size_t)b * Nn + n) * Ee + e] = oacc[nh][es][r] * invr;
                }
            }
        }
    }
}

// ---------- fp32 fallback (verified R1 kernel) for ws too small ----------
constexpr int FNT = 16, FLT = 64, FLTP = 65;
__global__ __launch_bounds__(256)
void cwa_fwd(const float* __restrict__ x, const float* __restrict__ lf,
             float* __restrict__ out) {
    __shared__ float q[FNT][Ee];
    __shared__ float xts[Ee][FLTP];
    __shared__ float pl[FNT][FLT];
    const int tid = threadIdx.x, lane = tid & 63, w = tid >> 6;
    const int b = blockIdx.y, n0 = blockIdx.x * FNT;
    for (int idx = tid; idx < FNT * Ee; idx += 256) {
        int nl = idx / Ee, e = idx - nl * Ee;
        int n = n0 + nl;
        q[nl][e] = (n < Nn) ? lf[n * Ee + e] : 0.0f;
    }
    float m_i[4], s_i[4], a0[4], a1[4];
#pragma unroll
    for (int i = 0; i < 4; i++) { m_i[i] = -INFINITY; s_i[i] = 0.f; a0[i] = 0.f; a1[i] = 0.f; }
    const float* xb = x + (size_t)b * Ll * Ee;
    const bool hi_ok = lane < (Ee - 64);
    for (int l0 = 0; l0 < Ll; l0 += FLT) {
        const int nrows = min(FLT, Ll - l0);
        __syncthreads();
        for (int idx = tid; idx < FLT * (Ee / 4); idx += 256) {
            int r = idx / (Ee / 4), c4 = idx - r * (Ee / 4);
            float4 v = make_float4(0.f, 0.f, 0.f, 0.f);
            if (r < nrows) v = *reinterpret_cast<const float4*>(xb + (size_t)(l0 + r) * Ee + c4 * 4);
            xts[c4 * 4 + 0][r] = v.x; xts[c4 * 4 + 1][r] = v.y;
            xts[c4 * 4 + 2][r] = v.z; xts[c4 * 4 + 3][r] = v.w;
        }
        __syncthreads();
        float sc[4] = {0.f, 0.f, 0.f, 0.f};
        for (int e = 0; e < Ee; e++) {
            float xv = xts[e][lane];
#pragma unroll
            for (int i = 0; i < 4; i++) sc[i] = fmaf(q[4 * w + i][e], xv, sc[i]);
        }
        const bool valid = lane < nrows;
#pragma unroll
        for (int i = 0; i < 4; i++) {
            float s = valid ? sc[i] : -INFINITY;
            float tmv = s;
#pragma unroll
            for (int msk = 32; msk >= 1; msk >>= 1) tmv = fmaxf(tmv, __shfl_xor(tmv, msk, 64));
            float mn = fmaxf(m_i[i], tmv);
            float pp = __expf(s - mn);
            float sm = pp;
#pragma unroll
            for (int msk = 32; msk >= 1; msk >>= 1) sm += __shfl_xor(sm, msk, 64);
            float scl = __expf(m_i[i] - mn);
            s_i[i] = s_i[i] * scl + sm; m_i[i] = mn;
            a0[i] *= scl; a1[i] *= scl;
            pl[4 * w + i][lane] = pp;
        }
        __syncthreads();
#pragma unroll 4
        for (int l = 0; l < FLT; l++) {
            float xv0 = xts[lane][l];
            float xv1 = hi_ok ? xts[64 + lane][l] : 0.f;
#pragma unroll
            for (int i = 0; i < 4; i++) {
                float pv = pl[4 * w + i][l];
                a0[i] = fmaf(pv, xv0, a0[i]); a1[i] = fmaf(pv, xv1, a1[i]);
            }
        }
    }
#pragma unroll
    for (int i = 0; i < 4; i++) {
        int n = n0 + 4 * w + i;
        if (n >= Nn) continue;
        float inv = 1.0f / s_i[i];
        size_t base = ((size_t)b * Nn + n) * Ee;
        out[base + lane] = a0[i] * inv;
        if (hi_ok) out[base + 64 + lane] = a1[i] * inv;
    }
}

extern "C" void kernel_launch(void* const* d_in, const int* in_sizes, int n_in,
                              void* d_out, int out_size, void* d_ws, size_t ws_size,
                              hipStream_t stream) {
    const float* x  = (const float*)d_in[0];   // [8, 2500, 100]
    const float* lf = (const float*)d_in[1];   // [8922, 100]
    float* out = (float*)d_out;                // [8, 8922, 100]
    if (ws_size >= WS_NEED) {
        uint32_t* dlf = (uint32_t*)d_ws;
        uint32_t* dxw = (uint32_t*)((char*)d_ws + OFF_XW);
        uint16_t* dxt = (uint16_t*)((char*)d_ws + OFF_XT);
        prep_all<<<dim3(LP / 64, Bb + 1), 256, 0, stream>>>(x, lf, dlf, dxw, dxt);
        cwa_mfma<<<dim3(NP / NTB, Bb), 256, 0, stream>>>(
            (const uint16_t*)dlf, (const uint16_t*)dxw, dxt, out);
    } else {
        dim3 grid((Nn + FNT - 1) / FNT, Bb);
        cwa_fwd<<<grid, dim3(256), 0, stream>>>(x, lf, out);
    }
}

// Round 7
// 234.677 us; speedup vs baseline: 1.2476x; 1.0168x over previous
//
#include <hip/hip_runtime.h>
#include <math.h>
#include <stdint.h>

typedef __attribute__((ext_vector_type(8))) _Float16 half8;
typedef __attribute__((ext_vector_type(16))) float f32x16;
typedef __attribute__((ext_vector_type(4))) uint32_t uint4v;

constexpr int Bb = 8, Ll = 2500, Ee = 100, Nn = 8922;
constexpr int LP = 2560, EP = 128, NP = 8960;    // padded dims
constexpr int VE = 112;                          // staged V^T rows
constexpr int LT = 64;
constexpr int NTILES = LP / LT;                  // 40
constexpr int NTB = 128;                         // 4 waves x 32 n

constexpr size_t SZ_LF = (size_t)NP * EP * 2;
constexpr size_t SZ_XW = (size_t)Bb * LP * EP * 2;
constexpr size_t SZ_XT = (size_t)Bb * VE * LP * 2;
constexpr size_t OFF_XW = SZ_LF;
constexpr size_t OFF_XT = OFF_XW + SZ_XW;
constexpr size_t WS_NEED = OFF_XT + SZ_XT;       // ~12.14 MB (same as R6, known-safe)

__device__ __forceinline__ void gload16(const void* g, void* l) {
    __builtin_amdgcn_global_load_lds(
        (const __attribute__((address_space(1))) uint32_t*)g,
        (__attribute__((address_space(3))) uint32_t*)l, 16, 0, 0);
}

// ---------- fused prepass ----------
// y<8 : x[b] -> swizzled K rows [B][LP][EP] f16 (bias e=127) + swizzled V^T [B][VE][LP]
// y==8: lf -> f16 [NP][EP], bias col e=127 = 1.0
__global__ __launch_bounds__(256)
void prep_all(const float* __restrict__ x, const float* __restrict__ lf,
              uint32_t* __restrict__ dlf, uint32_t* __restrict__ dxw,
              uint16_t* __restrict__ dxt) {
    if (blockIdx.y == Bb) {
        for (int idx = blockIdx.x * 256 + threadIdx.x; idx < NP * 64; idx += 40 * 256) {
            int n = idx >> 6, ep = idx & 63;
            int e0 = 2 * ep, e1 = e0 + 1;
            float f0 = (n < Nn && e0 < Ee) ? lf[(size_t)n * Ee + e0] : 0.f;
            float f1 = (n < Nn && e1 < Ee) ? lf[(size_t)n * Ee + e1] : (e1 == 127 ? 1.0f : 0.f);
            union { _Float16 h[2]; uint32_t u; } cv;
            cv.h[0] = (_Float16)f0; cv.h[1] = (_Float16)f1;
            dlf[idx] = cv.u;
        }
        return;
    }
    __shared__ float lx[64][101];
    const int l0 = blockIdx.x * 64;
    const int b  = blockIdx.y;
    for (int i = threadIdx.x; i < 64 * Ee; i += 256) {
        int ll = i / Ee, e = i - ll * Ee;
        int l = l0 + ll;
        lx[ll][e] = (l < Ll) ? x[((size_t)b * Ll + l) * Ee + e] : 0.f;
    }
    __syncthreads();
    // K rows: 16B-chunk XOR key (l&15) within 256B row; mask bias at e=127
    for (int i = threadIdx.x; i < 64 * 64; i += 256) {
        int row = i >> 6, ep = i & 63;
        int l = l0 + row;
        int e0 = 2 * ep, e1 = e0 + 1;
        float f0 = (e0 < Ee) ? lx[row][e0] : 0.f;
        float f1;
        if (e1 < Ee)        f1 = lx[row][e1];
        else if (e1 == 127) f1 = (l < Ll) ? 0.f : -20000.f;   // softmax mask bias
        else                f1 = 0.f;
        union { _Float16 h[2]; uint32_t u; } cv;
        cv.h[0] = (_Float16)f0; cv.h[1] = (_Float16)f1;
        int boff = (4 * ep) ^ ((row & 15) << 4);
        dxw[((size_t)b * LP + l) * 64 + (boff >> 2)] = cv.u;
    }
    // V^T rows: [e][l], 16B-chunk XOR key (e&7) within each tile's 128B (as R6)
    for (int i = threadIdx.x; i < VE * 64; i += 256) {
        int e = i >> 6, ll = i & 63;
        float v = (e < Ee) ? lx[ll][e] : 0.f;
        uint32_t boff = (uint32_t)((2 * ll) ^ ((e & 7) << 4));
        union { _Float16 h; uint16_t u; } cv; cv.h = (_Float16)v;
        dxt[((size_t)b * VE + e) * LP + l0 + (boff >> 1)] = cv.u;
    }
}

// ---------- main: 32x32 MFMA flash attention, in-register P, 3 blocks/CU ----------
__global__ __launch_bounds__(256, 3)
void cwa_mfma(const uint16_t* __restrict__ lf16, const uint16_t* __restrict__ xw,
              const uint16_t* __restrict__ xt, float* __restrict__ out) {
    // K dbuf 2x16K | V 16K (rows>=112 never staged/used-valid)  => 48 KB
    __shared__ __align__(128) char smem[49152];
    const int tid = threadIdx.x, lane = tid & 63, w = tid >> 6;
    const int r31 = lane & 31, hi = lane >> 5;
    const int o = blockIdx.x;
    const int b = o & 7, xb = o >> 3;          // XCD swizzle: one batch per XCD
    const int n_base = xb * NTB + w * 32;

    const char* xwb = (const char*)(xw + (size_t)b * LP * EP);
    const char* xtb = (const char*)(xt + (size_t)b * VE * LP);

    auto stage_k = [&](int t, int p) {
        const char* kg = xwb + (size_t)t * (LT * EP * 2);
        char* kbuf = smem + p * 16384;
#pragma unroll
        for (int i = 0; i < 4; i++) {
            int off = i * 4096 + tid * 16;
            gload16(kg + off, kbuf + off);
        }
    };
    auto stage_v = [&](int t) {
        const char* vg = xtb + (size_t)t * (LT * 2);
        char* vbuf = smem + 32768;
#pragma unroll
        for (int i = 0; i < 3; i++) {
            int u = i * 256 + tid;
            gload16(vg + (size_t)(u >> 3) * (LP * 2) + (u & 7) * 16, vbuf + u * 16);
        }
        if (tid < 128) {
            int u = 768 + tid;
            gload16(vg + (size_t)(u >> 3) * (LP * 2) + (u & 7) * 16, vbuf + u * 16);
        }
    };

    stage_k(0, 0);
    stage_v(0);

    // Q fragments (B-operand, 32x32x16): col n = r31, k = e = 16ks + 8hi + j
    half8 qf[8];
    {
        const uint16_t* qr = lf16 + (size_t)(n_base + r31) * EP + 8 * hi;
#pragma unroll
        for (int ks = 0; ks < 8; ks++) qf[ks] = *(const half8*)(qr + 16 * ks);
    }
    asm volatile("s_waitcnt vmcnt(0)" ::: "memory");
    __syncthreads();
    stage_k(1, 1);

    f32x16 oacc[4];
#pragma unroll
    for (int eb = 0; eb < 4; eb++)
#pragma unroll
        for (int r = 0; r < 16; r++) oacc[eb][r] = 0.f;
    float m_i = -INFINITY, s_i = 0.f;

    const char* vb = smem + 32768;
    const int kkey = r31 & 15;    // K chunk XOR key
    const int vkey = r31 & 7;     // V chunk XOR key

    for (int t = 0; t < NTILES; t++) {
        const int p = t & 1;
        const char* kb = smem + p * 16384;

        // ---- QK^T: S^T[l][n] = mfma(A=K, B=Q), 2 l-blocks x 8 k-steps ----
        f32x16 sacc[2];
#pragma unroll
        for (int lb = 0; lb < 2; lb++)
#pragma unroll
            for (int r = 0; r < 16; r++) sacc[lb][r] = 0.f;
#pragma unroll
        for (int lb = 0; lb < 2; lb++) {
            const char* kr = kb + (32 * lb + r31) * 256;
#pragma unroll
            for (int ks = 0; ks < 8; ks++) {
                half8 kf = *(const half8*)(kr + (((2 * ks + hi) ^ kkey) << 4));
                sacc[lb] = __builtin_amdgcn_mfma_f32_32x32x16_f16(kf, qf[ks], sacc[lb], 0, 0, 0);
            }
        }

        // ---- tile max over the lane's 32 l-values (col n = r31) ----
        float tmv = -INFINITY;
#pragma unroll
        for (int lb = 0; lb < 2; lb++)
#pragma unroll
            for (int r = 0; r < 16; r++) tmv = fmaxf(tmv, sacc[lb][r]);
        tmv = fmaxf(tmv, __shfl_xor(tmv, 32, 64));

        // ---- defer-max (T13) ----
        if (!__all(tmv <= m_i + 8.f)) {
            const float mn = fmaxf(m_i, tmv);
            const float sc = __expf(m_i - mn);       // first tile: exp(-inf)=0
            m_i = mn;
            s_i *= sc;
#pragma unroll
            for (int r = 0; r < 16; r++) {
                float scr = __shfl(sc, (r & 3) + 8 * (r >> 2) + 4 * hi, 64);
#pragma unroll
                for (int eb = 0; eb < 4; eb++) oacc[eb][r] *= scr;
            }
        }

        // ---- P = exp(S - m); pack to f16; in-register re-fragment (T12-style) ----
        half8 pa[4];
        float ts = 0.f;
#pragma unroll
        for (int lb = 0; lb < 2; lb++) {
            uint32_t c[8], xch[8];
#pragma unroll
            for (int i = 0; i < 8; i++) {
                float p0 = __expf(sacc[lb][2 * i]     - m_i);
                float p1 = __expf(sacc[lb][2 * i + 1] - m_i);
                ts += p0 + p1;
                c[i] = __builtin_bit_cast(uint32_t, __builtin_amdgcn_cvt_pkrtz(p0, p1));
            }
#pragma unroll
            for (int i = 0; i < 8; i++) xch[i] = __shfl_xor(c[i], 32, 64);
            uint4v wa = {hi ? xch[2] : c[0], hi ? xch[3] : c[1],
                         hi ? c[2] : xch[0], hi ? c[3] : xch[1]};
            uint4v wb2 = {hi ? xch[6] : c[4], hi ? xch[7] : c[5],
                          hi ? c[6] : xch[4], hi ? c[7] : xch[5]};
            pa[2 * lb]     = __builtin_bit_cast(half8, wa);
            pa[2 * lb + 1] = __builtin_bit_cast(half8, wb2);
        }
        ts += __shfl_xor(ts, 32, 64);
        s_i += ts;

        // ---- PV: D[n][e] += mfma(A=P, B=V), 4 e-blocks x 4 k-steps ----
#pragma unroll
        for (int eb = 0; eb < 4; eb++) {
            const char* vr = vb + (32 * eb + r31) * 128;
#pragma unroll
            for (int kk = 0; kk < 4; kk++) {
                half8 vf = *(const half8*)(vr + (((2 * kk + hi) ^ vkey) << 4));
                oacc[eb] = __builtin_amdgcn_mfma_f32_32x32x16_f16(pa[kk], vf, oacc[eb], 0, 0, 0);
            }
        }

        __syncthreads();                           // all waves done with vb & kb[p]
        const int tv = min(t + 1, NTILES - 1);
        const int tk = min(t + 2, NTILES - 1);
        stage_v(tv);
        stage_k(tk, p);
        asm volatile("s_waitcnt vmcnt(4)" ::: "memory");   // V(t+1) landed; K(t+2) in flight
        __syncthreads();
    }

    // ---- epilogue: out[b][n][e] = oacc/s ----
    const float inv = 1.0f / s_i;
#pragma unroll
    for (int r = 0; r < 16; r++) {
        const int nrow = (r & 3) + 8 * (r >> 2) + 4 * hi;
        const float invr = __shfl(inv, nrow, 64);
        const int n = n_base + nrow;
        if (n < Nn) {
            float* orow = out + ((size_t)b * Nn + n) * Ee;
            orow[r31]      = oacc[0][r] * invr;
            orow[32 + r31] = oacc[1][r] * invr;
            orow[64 + r31] = oacc[2][r] * invr;
            if (r31 < 4) orow[96 + r31] = oacc[3][r] * invr;
        }
    }
}

// ---------- fp32 fallback (verified R1 kernel) for ws too small ----------
constexpr int FNT = 16, FLT = 64, FLTP = 65;
__global__ __launch_bounds__(256)
void cwa_fwd(const float* __restrict__ x, const float* __restrict__ lf,
             float* __restrict__ out) {
    __shared__ float q[FNT][Ee];
    __shared__ float xts[Ee][FLTP];
    __shared__ float pl[FNT][FLT];
    const int tid = threadIdx.x, lane = tid & 63, w = tid >> 6;
    const int b = blockIdx.y, n0 = blockIdx.x * FNT;
    for (int idx = tid; idx < FNT * Ee; idx += 256) {
        int nl = idx / Ee, e = idx - nl * Ee;
        int n = n0 + nl;
        q[nl][e] = (n < Nn) ? lf[n * Ee + e] : 0.0f;
    }
    float m_i[4], s_i[4], a0[4], a1[4];
#pragma unroll
    for (int i = 0; i < 4; i++) { m_i[i] = -INFINITY; s_i[i] = 0.f; a0[i] = 0.f; a1[i] = 0.f; }
    const float* xb = x + (size_t)b * Ll * Ee;
    const bool hi_ok = lane < (Ee - 64);
    for (int l0 = 0; l0 < Ll; l0 += FLT) {
        const int nrows = min(FLT, Ll - l0);
        __syncthreads();
        for (int idx = tid; idx < FLT * (Ee / 4); idx += 256) {
            int r = idx / (Ee / 4), c4 = idx - r * (Ee / 4);
            float4 v = make_float4(0.f, 0.f, 0.f, 0.f);
            if (r < nrows) v = *reinterpret_cast<const float4*>(xb + (size_t)(l0 + r) * Ee + c4 * 4);
            xts[c4 * 4 + 0][r] = v.x; xts[c4 * 4 + 1][r] = v.y;
            xts[c4 * 4 + 2][r] = v.z; xts[c4 * 4 + 3][r] = v.w;
        }
        __syncthreads();
        float sc[4] = {0.f, 0.f, 0.f, 0.f};
        for (int e = 0; e < Ee; e++) {
            float xv = xts[e][lane];
#pragma unroll
            for (int i = 0; i < 4; i++) sc[i] = fmaf(q[4 * w + i][e], xv, sc[i]);
        }
        const bool valid = lane < nrows;
#pragma unroll
        for (int i = 0; i < 4; i++) {
            float s = valid ? sc[i] : -INFINITY;
            float tmv = s;
#pragma unroll
            for (int msk = 32; msk >= 1; msk >>= 1) tmv = fmaxf(tmv, __shfl_xor(tmv, msk, 64));
            float mn = fmaxf(m_i[i], tmv);
            float pp = __expf(s - mn);
            float sm = pp;
#pragma unroll
            for (int msk = 32; msk >= 1; msk >>= 1) sm += __shfl_xor(sm, msk, 64);
            float scl = __expf(m_i[i] - mn);
            s_i[i] = s_i[i] * scl + sm; m_i[i] = mn;
            a0[i] *= scl; a1[i] *= scl;
            pl[4 * w + i][lane] = pp;
        }
        __syncthreads();
#pragma unroll 4
        for (int l = 0; l < FLT; l++) {
            float xv0 = xts[lane][l];
            float xv1 = hi_ok ? xts[64 + lane][l] : 0.f;
#pragma unroll
            for (int i = 0; i < 4; i++) {
                float pv = pl[4 * w + i][l];
                a0[i] = fmaf(pv, xv0, a0[i]); a1[i] = fmaf(pv, xv1, a1[i]);
            }
        }
    }
#pragma unroll
    for (int i = 0; i < 4; i++) {
        int n = n0 + 4 * w + i;
        if (n >= Nn) continue;
        float inv = 1.0f / s_i[i];
        size_t base = ((size_t)b * Nn + n) * Ee;
        out[base + lane] = a0[i] * inv;
        if (hi_ok) out[base + 64 + lane] = a1[i] * inv;
    }
}

extern "C" void kernel_launch(void* const* d_in, const int* in_sizes, int n_in,
                              void* d_out, int out_size, void* d_ws, size_t ws_size,
                              hipStream_t stream) {
    const float* x  = (const float*)d_in[0];   // [8, 2500, 100]
    const float* lf = (const float*)d_in[1];   // [8922, 100]
    float* out = (float*)d_out;                // [8, 8922, 100]
    if (ws_size >= WS_NEED) {
        uint32_t* dlf = (uint32_t*)d_ws;
        uint32_t* dxw = (uint32_t*)((char*)d_ws + OFF_XW);
        uint16_t* dxt = (uint16_t*)((char*)d_ws + OFF_XT);
        prep_all<<<dim3(LP / 64, Bb + 1), 256, 0, stream>>>(x, lf, dlf, dxw, dxt);
        cwa_mfma<<<dim3((NP / NTB) * Bb), 256, 0, stream>>>(
            (const uint16_t*)dlf, (const uint16_t*)dxw, dxt, out);
    } else {
        dim3 grid((Nn + FNT - 1) / FNT, Bb);
        cwa_fwd<<<grid, dim3(256), 0, stream>>>(x, lf, out);
    }
}